// Round 12
// baseline (3600.529 us; speedup 1.0000x reference)
//
#include <hip/hip_runtime.h>
#include <math.h>

// ---------------- problem constants ----------------
#define NNv    1024
#define BSZ    32
#define NINv   784
#define NOUTv  10
#define ALPHAc 0.9f
#define DTc    0.05f
#define EPSc   0.05f
#define MAXST  1000

// ---------------- launch geometry ----------------
#define GRIDv  256      // 1 block per CU; each block owns 4 rows of both layers
#define THRv   512      // 8 waves

// ---------------- workspace layout (float indices) ----------------
#define WS_XIN 0
#define WS_H0A 32768
#define WS_H0B 65536
#define WS_H1A 98304
#define WS_H1B 131072
#define WS_FLG 163840   // flag0[2][256] u64, then flag1[2][256] u64

typedef unsigned long long u64;
typedef float f4v __attribute__((ext_vector_type(4)));

struct Prm {
  const float *W_in, *b_in, *W_rec, *mask, *b_rec, *W_out, *b_out, *xin;
  float *h0a, *h0b, *h1a, *h1b, *out;
  u64 *flag0, *flag1;
};

__device__ __forceinline__ void fma4(f4v& a, const f4v h, const float w) {
  a.x = fmaf(h.x, w, a.x); a.y = fmaf(h.y, w, a.y);
  a.z = fmaf(h.z, w, a.z); a.w = fmaf(h.w, w, a.w);
}
__device__ __forceinline__ void red4(f4v& a, int m) {
  a.x += __shfl_xor(a.x, m); a.y += __shfl_xor(a.y, m);
  a.z += __shfl_xor(a.z, m); a.w += __shfl_xor(a.w, m);
}
__device__ __forceinline__ unsigned amax4bits(const f4v d) {
  float m = fmaxf(fmaxf(fabsf(d.x), fabsf(d.y)), fmaxf(fabsf(d.z), fabsf(d.w)));
  return __float_as_uint(m);   // fabs => bit31 clear; uint compare == float compare
}

// far-atomic 16B store: two u64 swaps execute AT the coherence point (MALL).
// Returning form (sc0): when vmcnt drains, the data is PROVABLY at MALL.
__device__ __forceinline__ void stg16_far(f4v* p, const f4v v) {
  u64 d0 = ((u64)__float_as_uint(v.y) << 32) | (u64)__float_as_uint(v.x);
  u64 d1 = ((u64)__float_as_uint(v.w) << 32) | (u64)__float_as_uint(v.z);
  u64 o0, o1;
  asm volatile(
    "global_atomic_swap_x2 %0, %2, %3, off sc0 sc1\n\t"
    "global_atomic_swap_x2 %1, %4, %5, off sc0 sc1"
    : "=&v"(o0), "=&v"(o1)
    : "v"(p), "v"(d0), "v"((char*)p + 8), "v"(d1)
    : "memory");
  asm volatile("" :: "v"(o0), "v"(o1));  // keep returned olds live
}

// x_in = X @ W_input^T + b_input, stored [i][b]; zero all four h state buffers
__global__ __launch_bounds__(256) void k_xin(const float* X, const float* Wi, const float* bi,
                                             float* xin, float* h0a, float* h0b,
                                             float* h1a, float* h1b) {
  int i  = blockIdx.x;
  int b  = threadIdx.x & 31;
  int fs = threadIdx.x >> 5;
  const float* xr = X  + b * NINv;
  const float* wr = Wi + i * NINv;
  float acc = 0.f;
  for (int f = fs; f < NINv; f += 8) acc = fmaf(xr[f], wr[f], acc);
  __shared__ float red[8][32];
  red[fs][b] = acc;
  __syncthreads();
  if (threadIdx.x < 32) {
    float s = bi[i];
    #pragma unroll
    for (int q = 0; q < 8; ++q) s += red[q][threadIdx.x];
    int off = i * BSZ + threadIdx.x;
    xin[off] = s;
    h0a[off] = 0.f; h0b[off] = 0.f; h1a[off] = 0.f; h1b[off] = 0.f;
  }
}

// Persistent kernel, ONE grid sync per Euler step, zero cache-maintenance ops.
// Release: h via far atomics + vmcnt(0) + flag store. Acquire: bypass reads.
// All 32 h loads in ONE asm block ending vmcnt(0): outputs valid at block exit
// (no compiler-spill hazard window), single latency exposure.
__global__ __launch_bounds__(THRv) void k_main(Prm p) {
  const int tid  = threadIdx.x;
  const int bid  = blockIdx.x;
  const int lane = tid & 63;
  const int wv   = tid >> 6;        // wave 0..7 -> j-slice [wv*128, wv*128+128)
  const int lg   = lane & 7;        // b-quad (b = lg*4..lg*4+3)
  const int jq   = lane >> 3;       // j sub-slice 0..7 (16 j each)

  __shared__ __align__(16) float wA [4096];   // Wm0  rows, transposed quads, XOR-swizzled
  __shared__ __align__(16) float wB1[4096];   // Win1 rows
  __shared__ __align__(16) float wBM[4096];   // Wm1  rows
  __shared__ __align__(16) f4v  part[64][8];  // [wv*8 + acc][lg]
  __shared__ __align__(16) f4v  h0own[4][8];  // this block's 4 rows of h0(t-1)
  __shared__ __align__(16) f4v  h1own[4][8];  // this block's 4 rows of h1(t-2)
  __shared__ __align__(16) float xin_s[4][32];
  __shared__ float bias0[4], bias1[4];
  __shared__ unsigned dmax[2][2];   // [parity][0: d0, 1: d1]

  // ---- stage weights into LDS: slot f4(j) = j ^ ((j>>4)&7) holds quad {w[r=0..3][j]} ----
  {
    const float* A  = p.W_rec;
    const float* M0 = p.mask;
    const float* B1 = p.W_in  + NNv*NNv;
    const float* BM = p.W_rec + NNv*NNv;
    const float* M1 = p.mask  + NNv*NNv;
    const int i0 = bid * 4;
    for (int idx = tid; idx < 4096; idx += THRv) {
      int j = idx & 1023, r = idx >> 10;
      int f = (j ^ ((j >> 4) & 7)) * 4 + r;
      int g = (i0 + r) * NNv + j;
      wA [f] = A [g] * M0[g];
      wB1[f] = B1[g];
      wBM[f] = BM[g] * M1[g];
    }
    if (tid < 128) xin_s[tid >> 5][tid & 31] = p.xin[(i0 + (tid >> 5)) * BSZ + (tid & 31)];
    if (tid < 4) {
      bias0[tid] = p.b_rec[i0 + tid];
      bias1[tid] = p.b_in[NNv + i0 + tid] + p.b_rec[NNv + i0 + tid];
    }
    if (tid == 0) { dmax[0][0] = dmax[0][1] = dmax[1][0] = dmax[1][1] = 0u; }
  }
  __syncthreads();

  const int jb  = wv * 128 + jq * 16;          // this thread's j base (16 quads)
  const int wv0 = bid >> 5;                    // wave holding this block's own rows
  const int jq0 = (bid >> 2) & 7;              // jq holding this block's own rows
  const bool ownth = (wv == wv0) && (jq == jq0);
  const f4v* A4  = ((const f4v*)wA );
  const f4v* B14 = ((const f4v*)wB1);
  const f4v* BM4 = ((const f4v*)wBM);

  unsigned prevD0b = 0u;
  int t = 1, K = MAXST;
  for (;;) {
    const int par = t & 1;
    const f4v* H0 = (const f4v*)(par ? p.h0a : p.h0b);  // h0(t-1)
    const f4v* H1 = (const f4v*)(par ? p.h1b : p.h1a);  // h1(t-2)
    float* h0w = par ? p.h0b : p.h0a;                   // h0(t)
    float* h1w = par ? p.h1a : p.h1b;                   // h1(t-1)

    // ---- matmul: 32 bypass loads in ONE asm block (single wait, outputs valid at exit) ----
    f4v aA0 = {0,0,0,0}, aA1 = aA0, aA2 = aA0, aA3 = aA0;
    f4v aB0 = aA0, aB1v = aA0, aB2 = aA0, aB3 = aA0;
    {
      const f4v* P0 = H0 + jb*8 + lg;
      const f4v* P1 = H1 + jb*8 + lg;
      f4v x00,x01,x02,x03,x04,x05,x06,x07,x08,x09,x10,x11,x12,x13,x14,x15;  // h0 rows jb..jb+15
      f4v y00,y01,y02,y03,y04,y05,y06,y07,y08,y09,y10,y11,y12,y13,y14,y15;  // h1 rows jb..jb+15
      asm volatile(
        "global_load_dwordx4 %0, %32, off sc0 sc1\n\t"
        "global_load_dwordx4 %1, %32, off offset:128 sc0 sc1\n\t"
        "global_load_dwordx4 %2, %32, off offset:256 sc0 sc1\n\t"
        "global_load_dwordx4 %3, %32, off offset:384 sc0 sc1\n\t"
        "global_load_dwordx4 %4, %32, off offset:512 sc0 sc1\n\t"
        "global_load_dwordx4 %5, %32, off offset:640 sc0 sc1\n\t"
        "global_load_dwordx4 %6, %32, off offset:768 sc0 sc1\n\t"
        "global_load_dwordx4 %7, %32, off offset:896 sc0 sc1\n\t"
        "global_load_dwordx4 %8, %32, off offset:1024 sc0 sc1\n\t"
        "global_load_dwordx4 %9, %32, off offset:1152 sc0 sc1\n\t"
        "global_load_dwordx4 %10, %32, off offset:1280 sc0 sc1\n\t"
        "global_load_dwordx4 %11, %32, off offset:1408 sc0 sc1\n\t"
        "global_load_dwordx4 %12, %32, off offset:1536 sc0 sc1\n\t"
        "global_load_dwordx4 %13, %32, off offset:1664 sc0 sc1\n\t"
        "global_load_dwordx4 %14, %32, off offset:1792 sc0 sc1\n\t"
        "global_load_dwordx4 %15, %32, off offset:1920 sc0 sc1\n\t"
        "global_load_dwordx4 %16, %33, off sc0 sc1\n\t"
        "global_load_dwordx4 %17, %33, off offset:128 sc0 sc1\n\t"
        "global_load_dwordx4 %18, %33, off offset:256 sc0 sc1\n\t"
        "global_load_dwordx4 %19, %33, off offset:384 sc0 sc1\n\t"
        "global_load_dwordx4 %20, %33, off offset:512 sc0 sc1\n\t"
        "global_load_dwordx4 %21, %33, off offset:640 sc0 sc1\n\t"
        "global_load_dwordx4 %22, %33, off offset:768 sc0 sc1\n\t"
        "global_load_dwordx4 %23, %33, off offset:896 sc0 sc1\n\t"
        "global_load_dwordx4 %24, %33, off offset:1024 sc0 sc1\n\t"
        "global_load_dwordx4 %25, %33, off offset:1152 sc0 sc1\n\t"
        "global_load_dwordx4 %26, %33, off offset:1280 sc0 sc1\n\t"
        "global_load_dwordx4 %27, %33, off offset:1408 sc0 sc1\n\t"
        "global_load_dwordx4 %28, %33, off offset:1536 sc0 sc1\n\t"
        "global_load_dwordx4 %29, %33, off offset:1664 sc0 sc1\n\t"
        "global_load_dwordx4 %30, %33, off offset:1792 sc0 sc1\n\t"
        "global_load_dwordx4 %31, %33, off offset:1920 sc0 sc1\n\t"
        "s_waitcnt vmcnt(0)"
        : "=&v"(x00),"=&v"(x01),"=&v"(x02),"=&v"(x03),
          "=&v"(x04),"=&v"(x05),"=&v"(x06),"=&v"(x07),
          "=&v"(x08),"=&v"(x09),"=&v"(x10),"=&v"(x11),
          "=&v"(x12),"=&v"(x13),"=&v"(x14),"=&v"(x15),
          "=&v"(y00),"=&v"(y01),"=&v"(y02),"=&v"(y03),
          "=&v"(y04),"=&v"(y05),"=&v"(y06),"=&v"(y07),
          "=&v"(y08),"=&v"(y09),"=&v"(y10),"=&v"(y11),
          "=&v"(y12),"=&v"(y13),"=&v"(y14),"=&v"(y15)
        : "v"(P0), "v"(P1)
        : "memory");
      __builtin_amdgcn_sched_barrier(0);
      // stash this block's own 4 rows (h0(t-1), h1(t-2)) into LDS for the epilogue
      if (ownth) {
        switch (bid & 3) {
          case 0: h0own[0][lg]=x00; h0own[1][lg]=x01; h0own[2][lg]=x02; h0own[3][lg]=x03;
                  h1own[0][lg]=y00; h1own[1][lg]=y01; h1own[2][lg]=y02; h1own[3][lg]=y03; break;
          case 1: h0own[0][lg]=x04; h0own[1][lg]=x05; h0own[2][lg]=x06; h0own[3][lg]=x07;
                  h1own[0][lg]=y04; h1own[1][lg]=y05; h1own[2][lg]=y06; h1own[3][lg]=y07; break;
          case 2: h0own[0][lg]=x08; h0own[1][lg]=x09; h0own[2][lg]=x10; h0own[3][lg]=x11;
                  h1own[0][lg]=y08; h1own[1][lg]=y09; h1own[2][lg]=y10; h1own[3][lg]=y11; break;
          default:h0own[0][lg]=x12; h0own[1][lg]=x13; h0own[2][lg]=x14; h0own[3][lg]=x15;
                  h1own[0][lg]=y12; h1own[1][lg]=y13; h1own[2][lg]=y14; h1own[3][lg]=y15; break;
        }
      }
      #define MMSTEP(XQ, YQ, S2) { \
        const int f_ = jb + ((S2) ^ jq); \
        const f4v wa = A4[f_], w1 = B14[f_], wm = BM4[f_]; \
        fma4(aA0, XQ, wa.x); fma4(aA1, XQ, wa.y); fma4(aA2, XQ, wa.z); fma4(aA3, XQ, wa.w); \
        fma4(aB0, XQ, w1.x); fma4(aB1v,XQ, w1.y); fma4(aB2, XQ, w1.z); fma4(aB3, XQ, w1.w); \
        fma4(aB0, YQ, wm.x); fma4(aB1v,YQ, wm.y); fma4(aB2, YQ, wm.z); fma4(aB3, YQ, wm.w); }
      MMSTEP(x00, y00, 0)   MMSTEP(x01, y01, 1)
      MMSTEP(x02, y02, 2)   MMSTEP(x03, y03, 3)
      MMSTEP(x04, y04, 4)   MMSTEP(x05, y05, 5)
      MMSTEP(x06, y06, 6)   MMSTEP(x07, y07, 7)
      MMSTEP(x08, y08, 8)   MMSTEP(x09, y09, 9)
      MMSTEP(x10, y10, 10)  MMSTEP(x11, y11, 11)
      MMSTEP(x12, y12, 12)  MMSTEP(x13, y13, 13)
      MMSTEP(x14, y14, 14)  MMSTEP(x15, y15, 15)
      #undef MMSTEP
    }
    red4(aA0,8); red4(aA0,16); red4(aA0,32);
    red4(aA1,8); red4(aA1,16); red4(aA1,32);
    red4(aA2,8); red4(aA2,16); red4(aA2,32);
    red4(aA3,8); red4(aA3,16); red4(aA3,32);
    red4(aB0,8); red4(aB0,16); red4(aB0,32);
    red4(aB1v,8); red4(aB1v,16); red4(aB1v,32);
    red4(aB2,8); red4(aB2,16); red4(aB2,32);
    red4(aB3,8); red4(aB3,16); red4(aB3,32);
    if (jq == 0) {
      part[wv*8 + 0][lg] = aA0;  part[wv*8 + 1][lg] = aA1;
      part[wv*8 + 2][lg] = aA2;  part[wv*8 + 3][lg] = aA3;
      part[wv*8 + 4][lg] = aB0;  part[wv*8 + 5][lg] = aB1v;
      part[wv*8 + 6][lg] = aB2;  part[wv*8 + 7][lg] = aB3;
    }
    __syncthreads();

    // ---- epilogue (wave 0): cross-wave sum + sin/update + far-atomic store + flag ----
    if (wv == 0) {
      const int a = jq;                       // 0..3: layer0 row a; 4..7: layer1 row a-4
      f4v S = part[a][lg];
      #pragma unroll
      for (int w = 1; w < 8; ++w) {
        const f4v q = part[w*8 + a][lg];
        S.x += q.x; S.y += q.y; S.z += q.z; S.w += q.w;
      }
      const int r = a & 3;
      const int i = (bid << 2) + r;
      unsigned d0b = 0u, d1b = 0u;
      if (a < 4) {
        const f4v  xs = *((const f4v*)&xin_s[r][lg*4]);
        const float bx = bias0[r];
        const f4v  ho = h0own[r][lg];          // from LDS stash (no MALL re-read)
        f4v dh, hn;
        float sx;
        sx = S.x + xs.x + bx; dh.x = fmaf(-ALPHAc, ho.x, sinf(sx)); hn.x = fmaf(dh.x, DTc, ho.x);
        sx = S.y + xs.y + bx; dh.y = fmaf(-ALPHAc, ho.y, sinf(sx)); hn.y = fmaf(dh.y, DTc, ho.y);
        sx = S.z + xs.z + bx; dh.z = fmaf(-ALPHAc, ho.z, sinf(sx)); hn.z = fmaf(dh.z, DTc, ho.z);
        sx = S.w + xs.w + bx; dh.w = fmaf(-ALPHAc, ho.w, sinf(sx)); hn.w = fmaf(dh.w, DTc, ho.w);
        stg16_far(((f4v*)h0w) + i*8 + lg, hn);
        d0b = amax4bits(dh);
      } else if (t >= 2) {
        const float bx = bias1[r];
        const f4v  ho = h1own[r][lg];          // from LDS stash
        f4v dh, hn;
        float sx;
        sx = S.x + bx; dh.x = fmaf(-ALPHAc, ho.x, sinf(sx)); hn.x = fmaf(dh.x, DTc, ho.x);
        sx = S.y + bx; dh.y = fmaf(-ALPHAc, ho.y, sinf(sx)); hn.y = fmaf(dh.y, DTc, ho.y);
        sx = S.z + bx; dh.z = fmaf(-ALPHAc, ho.z, sinf(sx)); hn.z = fmaf(dh.z, DTc, ho.z);
        sx = S.w + bx; dh.w = fmaf(-ALPHAc, ho.w, sinf(sx)); hn.w = fmaf(dh.w, DTc, ho.w);
        stg16_far(((f4v*)h1w) + i*8 + lg, hn);
        d1b = amax4bits(dh);
      }
      #pragma unroll
      for (int m = 1; m < 64; m <<= 1) {
        const unsigned o0 = __shfl_xor(d0b, m), o1 = __shfl_xor(d1b, m);
        d0b = d0b > o0 ? d0b : o0;  d1b = d1b > o1 ? d1b : o1;
      }
      if (lane == 0) {
        // RELEASE: vmcnt(0) waits for all the wave's atomic returns => h at MALL.
        asm volatile("s_waitcnt vmcnt(0)" ::: "memory");
        const u64 tg = (u64)(unsigned)t << 32;
        __hip_atomic_store(p.flag0 + par*GRIDv + bid, tg | (u64)d0b,
                           __ATOMIC_RELAXED, __HIP_MEMORY_SCOPE_AGENT);
        __hip_atomic_store(p.flag1 + par*GRIDv + bid, tg | (u64)d1b,
                           __ATOMIC_RELAXED, __HIP_MEMORY_SCOPE_AGENT);
      }
    }

    // ---- flag barrier: waves 0-3 poll flag0, waves 4-7 poll flag1 (parallel) ----
    {
      const int  ps  = tid & 255;
      const u64  tag = (u64)(unsigned)t;
      u64* base = (tid < 256) ? (p.flag0 + par*GRIDv) : (p.flag1 + par*GRIDv);
      u64 v;
      do { v = __hip_atomic_load(base + ps, __ATOMIC_RELAXED, __HIP_MEMORY_SCOPE_AGENT); }
      while ((v >> 32) != tag);
      unsigned m = (unsigned)v;
      #pragma unroll
      for (int s = 1; s < 64; s <<= 1) {
        const unsigned o = __shfl_xor(m, s);
        m = m > o ? m : o;
      }
      if (lane == 0) atomicMax(&dmax[par][tid < 256 ? 0 : 1], m);
    }
    if (tid == THRv - 1) { dmax[par ^ 1][0] = 0u; dmax[par ^ 1][1] = 0u; }  // reset for next iter
    __syncthreads();

    const unsigned D0b = dmax[par][0];   // max|dh0(t)|
    const unsigned D1b = dmax[par][1];   // max|dh1(t-1)|
    if (t >= 2) {
      const unsigned Db = prevD0b > D1b ? prevD0b : D1b;  // D(t-1), NaN-bits sort high
      const float D = __uint_as_float(Db);
      if (!(D >= EPSc) || (t - 1) >= MAXST) { K = t - 1; break; }  // matches JAX cond
    }
    prevD0b = D0b;
    ++t;
  }

  // ---- output: out = h1(K) @ W_out^T + b_out (blocks 0..9, one output column each) ----
  __syncthreads();
  if (bid < NOUTv) {
    const float* h1f = (K & 1) ? p.h1b : p.h1a;
    const int o  = bid;
    const int b  = tid & 31;
    const int ig = tid >> 5;               // 16 i-slices of 64
    const float* wrow = p.W_out + o * NNv;
    float acc = 0.f;
    for (int qq = 0; qq < 8; ++qq) {
      const int i0 = (ig << 6) + qq * 8;
      const float* q0 = h1f + i0 * BSZ + b;
      float v0,v1,v2,v3,v4,v5,v6,v7;
      asm volatile(
        "global_load_dword %0, %8, off sc0 sc1\n\t"
        "global_load_dword %1, %8, off offset:128 sc0 sc1\n\t"
        "global_load_dword %2, %8, off offset:256 sc0 sc1\n\t"
        "global_load_dword %3, %8, off offset:384 sc0 sc1\n\t"
        "global_load_dword %4, %8, off offset:512 sc0 sc1\n\t"
        "global_load_dword %5, %8, off offset:640 sc0 sc1\n\t"
        "global_load_dword %6, %8, off offset:768 sc0 sc1\n\t"
        "global_load_dword %7, %8, off offset:896 sc0 sc1\n\t"
        "s_waitcnt vmcnt(0)"
        : "=&v"(v0),"=&v"(v1),"=&v"(v2),"=&v"(v3),
          "=&v"(v4),"=&v"(v5),"=&v"(v6),"=&v"(v7)
        : "v"(q0) : "memory");
      acc = fmaf(v0, wrow[i0+0], acc);
      acc = fmaf(v1, wrow[i0+1], acc);
      acc = fmaf(v2, wrow[i0+2], acc);
      acc = fmaf(v3, wrow[i0+3], acc);
      acc = fmaf(v4, wrow[i0+4], acc);
      acc = fmaf(v5, wrow[i0+5], acc);
      acc = fmaf(v6, wrow[i0+6], acc);
      acc = fmaf(v7, wrow[i0+7], acc);
    }
    float* sr = wA;                        // weights no longer needed
    sr[ig*32 + b] = acc;
    __syncthreads();
    if (tid < 32) {
      float s = p.b_out[o];
      #pragma unroll
      for (int q = 0; q < 16; ++q) s += sr[q*32 + tid];
      p.out[tid*NOUTv + o] = s;            // out[b][o]
    }
  }
}

extern "C" void kernel_launch(void* const* d_in, const int* in_sizes, int n_in,
                              void* d_out, int out_size, void* d_ws, size_t ws_size,
                              hipStream_t stream) {
  const float* X       = (const float*)d_in[0];
  const float* W_input = (const float*)d_in[1];
  const float* b_input = (const float*)d_in[2];
  const float* W_in    = (const float*)d_in[3];
  const float* b_in    = (const float*)d_in[4];
  const float* W_rec   = (const float*)d_in[5];
  const float* mask    = (const float*)d_in[6];
  const float* b_rec   = (const float*)d_in[7];
  const float* W_out   = (const float*)d_in[8];
  const float* b_out   = (const float*)d_in[9];
  (void)in_sizes; (void)n_in; (void)out_size; (void)ws_size;

  float* ws = (float*)d_ws;
  Prm p;
  p.W_in  = W_in;  p.b_in  = b_in;  p.W_rec = W_rec; p.mask = mask;
  p.b_rec = b_rec; p.W_out = W_out; p.b_out = b_out;
  p.xin = ws + WS_XIN;
  p.h0a = ws + WS_H0A; p.h0b = ws + WS_H0B;
  p.h1a = ws + WS_H1A; p.h1b = ws + WS_H1B;
  p.flag0 = (u64*)(ws + WS_FLG);
  p.flag1 = p.flag0 + 2 * GRIDv;
  p.out  = (float*)d_out;

  k_xin<<<NNv, 256, 0, stream>>>(X, W_input, b_input,
                                 (float*)p.xin, p.h0a, p.h0b, p.h1a, p.h1b);
  k_main<<<GRIDv, THRv, 0, stream>>>(p);
}